// Round 8
// baseline (243.941 us; speedup 1.0000x reference)
//
#include <hip/hip_runtime.h>
#include <hip/hip_bf16.h>
#include <stdint.h>

typedef __hip_bfloat16 bf16;
typedef __attribute__((ext_vector_type(8))) short short8;
typedef __attribute__((ext_vector_type(4))) float float4v;
typedef __attribute__((ext_vector_type(2))) float f2v;

#define NVOCAB 113
#define NPAIR (113 * 113)   // 12769
#define DDIM 128
#define HIDDIM 512
#define PAIRS_PB 16         // pairs per block
#define ROWS_PB 32          // rows per block

// fp32 pool element offsets (only biases used)
#define OFF_B1  145792
#define OFF_B2  211840

// bf16 transposed weight pool wb (element offsets)
#define BOFF_WOT 0                         // WOT[d][hk] = W_O[hk][d]     128x128
#define BOFF_W1T 16384                     // W1T[n][d]  = W1[d][n]       512x128
#define BOFF_W2T (16384 + 65536)           // W2T[d][j]  = W2[j][d]       128x512
#define BOFF_WUP (16384 + 65536 + 65536)   // WUP[v][d]  = W_U[v][d]|0    128x128
#define BTOTAL   (16384 + 65536 + 65536 + 16384)  // 163840

__device__ __forceinline__ uint16_t f2b(float f) {
  bf16 h = __float2bfloat16(f);
  return *(uint16_t*)&h;
}
__device__ __forceinline__ float b2f(uint16_t u) {
  return __uint_as_float(((uint32_t)u) << 16);
}
__device__ __forceinline__ float ldsrc(const void* p, int i, int isb) {
  return isb ? b2f(((const uint16_t*)p)[i]) : ((const float*)p)[i];
}

// LDS-only barrier: waits ds ops (cross-wave LDS visibility) but leaves
// global loads (vmcnt) IN FLIGHT across the barrier — avoids the compiler's
// full vmcnt(0) drain that __syncthreads() emits. All inter-wave
// communication in pair_mfma is through LDS, so this is sufficient.
__device__ __forceinline__ void bar_lds() {
  asm volatile("s_waitcnt lgkmcnt(0)\n\ts_barrier" ::: "memory");
}

// per-wave dtype self-detection: 64 samples of tok_emb raw u32s.
__device__ __forceinline__ int detect_isb(const uint32_t* __restrict__ tok_raw) {
  uint32_t u = tok_raw[threadIdx.x & 63];
  int e = (u >> 7) & 0xff;
  unsigned long long m = __ballot(e >= 100 && e <= 126);
  return __popcll(m) >= 48;
}

struct SrcPtrs { const void* p[11]; };
// p[0]=tok p[1]=pos p[2]=WQ p[3]=WK p[4]=WV p[5]=WO p[6]=W1 p[7]=b1 p[8]=W2 p[9]=b2 p[10]=WU

// ---------------- K1: all prep in one launch, sources read directly --------
__global__ void __launch_bounds__(384) build_kernel(
    SrcPtrs sp, float* __restrict__ wf,
    float* __restrict__ resid_pre, float* __restrict__ qt,
    float* __restrict__ kt, float* __restrict__ vt,
    uint16_t* __restrict__ wb) {
  const int tid = threadIdx.x;
  const int blk = blockIdx.x;
  const int isb = detect_isb((const uint32_t*)sp.p[0]);

  if (blk < 226) {
    // ---- qkv + resid ----
    const int row = blk;
    const int t = row >> 1, p = row & 1;
    __shared__ float r[DDIM];
    if (tid < DDIM) {
      float rv = ldsrc(sp.p[0], t * DDIM + tid, isb) +
                 ldsrc(sp.p[1], p * DDIM + tid, isb);
      r[tid] = rv;
      resid_pre[row * DDIM + tid] = rv;
    }
    __syncthreads();
    const int which = tid >> 7, jj = tid & 127;
    const int h = jj >> 5, j = jj & 31;
    const void* wsrc = sp.p[2 + which];
    const int base = h * 4096 + j;
    float a = 0.f;
    if (isb) {
      const uint16_t* w16 = (const uint16_t*)wsrc;
      #pragma unroll 8
      for (int d = 0; d < 128; ++d)
        a += r[d] * b2f(w16[base + d * 32]);
    } else {
      const float* w32 = (const float*)wsrc;
      #pragma unroll 8
      for (int d = 0; d < 128; ++d)
        a += r[d] * w32[base + d * 32];
    }
    float* outp = (which == 0) ? qt : (which == 1) ? kt : vt;
    outp[row * DDIM + jj] = a;
  } else if (blk < 653) {
    // ---- wb build ----
    const int idx = (blk - 226) * 384 + tid;
    if (idx < BTOTAL) {
      float v;
      if (idx < BOFF_W1T) {                       // WOT[d][c] = W_O[c*128+d]
        int l = idx, d = l >> 7, c = l & 127;
        v = ldsrc(sp.p[5], c * 128 + d, isb);
      } else if (idx < BOFF_W2T) {                // W1T[n][d] = W1[d*512+n]
        int l = idx - BOFF_W1T, n = l >> 7, d = l & 127;
        v = ldsrc(sp.p[6], d * 512 + n, isb);
      } else if (idx < BOFF_WUP) {                // W2T[d][j] = W2[j*128+d]
        int l = idx - BOFF_W2T, d = l >> 9, j = l & 511;
        v = ldsrc(sp.p[8], j * 128 + d, isb);
      } else {                                    // WUP[v][d] = W_U[v*128+d] or 0
        int l = idx - BOFF_WUP, vv = l >> 7, d = l & 127;
        v = (vv < NVOCAB) ? ldsrc(sp.p[10], vv * 128 + d, isb) : 0.f;
      }
      wb[idx] = f2b(v);
    }
  } else {
    // ---- biases ----
    const int i = (blk - 653) * 384 + tid;
    if (i < 512) wf[OFF_B1 + i] = ldsrc(sp.p[7], i, isb);
    else if (i < 640) wf[OFF_B2 + (i - 512)] = ldsrc(sp.p[9], i - 512, isb);
  }
}

// ---------------- K2: fused MFMA kernel, 16 pairs (32 rows) / block -------
// Cross-barrier weight pipeline + LDS-only barriers: prefetched B-operands
// genuinely stay in flight across barriers now (no vmcnt(0) drain).
// MFMA accumulation order identical to R4-R7 -> bit-identical output.
__global__ void __launch_bounds__(512, 2) pair_mfma_kernel(
    const float* __restrict__ resid_pre, const float* __restrict__ qt,
    const float* __restrict__ kt, const float* __restrict__ vt,
    const float* __restrict__ wf, const uint16_t* __restrict__ wb,
    float* __restrict__ table) {
  __shared__ uint16_t bufH[ROWS_PB * 512];   // 32 KB (H staging)
  __shared__ uint16_t bufZ[ROWS_PB * 128];   // 8 KB (Z, then R)
  __shared__ uint16_t bufS[ROWS_PB * 128];   // 8 KB (smid bf16)
  __shared__ float    spat[PAIRS_PB * 16];

  const int tid = threadIdx.x;
  const int blk = blockIdx.x;
  const int lane = tid & 63;
  const int npar = tid >> 6;            // wave id 0..7
  const int l15 = lane & 15, quad = lane >> 4;

  #define ROW_OF(row_) ({                                        \
    int pr_ = blk * PAIRS_PB + ((row_) >> 1);                    \
    if (pr_ >= NPAIR) pr_ = NPAIR - 1;                           \
    int t0_ = pr_ / NVOCAB, t1_ = pr_ - t0_ * NVOCAB;            \
    ((row_) & 1) ? t1_ * 2 + 1 : t0_ * 2; })

  // ---- top-of-kernel prefetches (ride the prologue latency) ----
  const int nG = npar * 16 + l15;       // N=128 column for GEMM0/2/3

  // GEMM0 B-operands issued at the very top
  short8 bW0[4];
  {
    const uint16_t* bp = wb + BOFF_WOT + nG * 128 + quad * 8;
    #pragma unroll
    for (int ks = 0; ks < 4; ++ks) bW0[ks] = *(const short8*)(bp + ks * 32);
  }

  float rpre[2][4];
  #pragma unroll
  for (int mf = 0; mf < 2; ++mf)
    #pragma unroll
    for (int r = 0; r < 4; ++r)
      rpre[mf][r] = resid_pre[ROW_OF(mf * 16 + quad * 4 + r) * DDIM + nG];
  float bias1v[4];
  #pragma unroll
  for (int ni = 0; ni < 4; ++ni)
    bias1v[ni] = wf[OFF_B1 + (npar + ni * 8) * 16 + l15];
  const float bias2 = wf[OFF_B2 + nG];
  // vt rows for the Z phase: 2 rows x 8 cols
  const int zm = tid >> 4, zc0 = (tid & 15) * 8;
  float4 zv0a, zv0b, zv1a, zv1b;
  {
    const int zr0 = ROW_OF((zm >> 1) * 2);
    const int zr1 = ROW_OF((zm >> 1) * 2 + 1);
    const float4* p0 = (const float4*)(vt + zr0 * DDIM + zc0);
    const float4* p1 = (const float4*)(vt + zr1 * DDIM + zc0);
    zv0a = p0[0]; zv0b = p0[1]; zv1a = p1[0]; zv1b = p1[1];
  }

  // ---- fused scores + softmax + blend (128 threads, no mid-barrier) ----
  // thread (pl, s): s = h*2 + qp; computes BOTH sp=0/1 scores itself.
  if (tid < 128) {
    const int pl = tid >> 3, s = tid & 7;
    int pair = blk * PAIRS_PB + pl;
    if (pair >= NPAIR) pair = NPAIR - 1;           // clamp: results discarded
    const int t0 = pair / NVOCAB, t1 = pair - t0 * NVOCAB;
    const int row0 = t0 * 2, row1 = t1 * 2 + 1;
    const int h = s >> 1, qp = s & 1;
    const float4* qrow = (const float4*)(qt + (qp ? row1 : row0) * DDIM + h * 32);
    const float4* k0r  = (const float4*)(kt + row0 * DDIM + h * 32);
    const float4* k1r  = (const float4*)(kt + row1 * DDIM + h * 32);
    float acc0 = 0.f, acc1 = 0.f;
    #pragma unroll
    for (int j = 0; j < 8; ++j) {
      float4 qv = qrow[j], kv0 = k0r[j], kv1 = k1r[j];
      acc0 += qv.x * kv0.x + qv.y * kv0.y + qv.z * kv0.z + qv.w * kv0.w;
      acc1 += qv.x * kv1.x + qv.y * kv1.y + qv.z * kv1.z + qv.w * kv1.w;
    }
    float s0 = acc0 * 0.17677669529663687f;
    float s1 = acc1 * 0.17677669529663687f;
    float m = fmaxf(s0, s1);
    float e0 = __expf(s0 - m), e1 = __expf(s1 - m);
    float inv = 1.f / (e0 + e1);
    spat[pl * 16 + s * 2]     = 0.5f + 0.5f * e0 * inv;
    spat[pl * 16 + s * 2 + 1] = 0.5f + 0.5f * e1 * inv;
  }
  bar_lds();

  // ---- Z = pattern-weighted V (prefetched), staged bf16 ----
  {
    const int pl = zm >> 1, qp = zm & 1;
    const int h = zc0 >> 5;
    const float p0 = spat[pl * 16 + h * 4 + qp * 2];
    const float p1 = spat[pl * 16 + h * 4 + qp * 2 + 1];
    float v0[8] = {zv0a.x, zv0a.y, zv0a.z, zv0a.w, zv0b.x, zv0b.y, zv0b.z, zv0b.w};
    float v1[8] = {zv1a.x, zv1a.y, zv1a.z, zv1a.w, zv1b.x, zv1b.y, zv1b.z, zv1b.w};
    short8 pk;
    #pragma unroll
    for (int e = 0; e < 8; ++e)
      pk[e] = (short)f2b(p0 * v0[e] + p1 * v1[e]);
    *(short8*)&bufZ[(zm * 16 + ((zc0 >> 3) ^ (zm & 15))) * 8] = pk;
  }
  bar_lds();

  float smid[2][4];
  short8 bW1a[2][4];                     // GEMM1 half0 weights (cross-barrier)

  // ---- GEMM0: smid = Z x WOT + resid  (N=128, K=128) ----
  {
    short8 af[2][4];
    #pragma unroll
    for (int mf = 0; mf < 2; ++mf)
      #pragma unroll
      for (int ks = 0; ks < 4; ++ks)
        af[mf][ks] = *(const short8*)&bufZ[((mf * 16 + l15) * 16 +
                                           ((ks * 4 + quad) ^ l15)) * 8];
    float4v acc[2] = {{0.f, 0.f, 0.f, 0.f}, {0.f, 0.f, 0.f, 0.f}};
    #pragma unroll
    for (int mf = 0; mf < 2; ++mf)
      #pragma unroll
      for (int ks = 0; ks < 4; ++ks)
        acc[mf] = __builtin_amdgcn_mfma_f32_16x16x32_bf16(af[mf][ks], bW0[ks],
                                                          acc[mf], 0, 0, 0);
    // issue GEMM1 half0 B-loads BEFORE the stores + barrier (stay in flight)
    #pragma unroll
    for (int nj = 0; nj < 2; ++nj) {
      const int n = (npar + nj * 8) * 16 + l15;
      const uint16_t* bp = wb + BOFF_W1T + n * 128 + quad * 8;
      #pragma unroll
      for (int ks = 0; ks < 4; ++ks)
        bW1a[nj][ks] = *(const short8*)(bp + ks * 32);
    }
    #pragma unroll
    for (int mf = 0; mf < 2; ++mf)
      #pragma unroll
      for (int r = 0; r < 4; ++r) {
        const int row = mf * 16 + quad * 4 + r;
        float v = acc[mf][r] + rpre[mf][r];
        smid[mf][r] = v;
        bufS[(row * 16 + ((nG >> 3) ^ (row & 15))) * 8 + (nG & 7)] = f2b(v);
      }
  }
  bar_lds();

  short8 bB2a[8];                        // GEMM2 half0 weights (cross-barrier)

  // ---- GEMM1: H = relu(smid x W1 + b1)  (N=512, K=128) ----
  {
    short8 af[2][4];
    #pragma unroll
    for (int mf = 0; mf < 2; ++mf)
      #pragma unroll
      for (int ks = 0; ks < 4; ++ks)
        af[mf][ks] = *(const short8*)&bufS[((mf * 16 + l15) * 16 +
                                           ((ks * 4 + quad) ^ l15)) * 8];
    // half 0: ni = 0,1 (weights already in flight)
    #pragma unroll
    for (int nj = 0; nj < 2; ++nj) {
      const int ni = nj;
      const int n = (npar + ni * 8) * 16 + l15;
      float4v acc[2] = {{0.f, 0.f, 0.f, 0.f}, {0.f, 0.f, 0.f, 0.f}};
      #pragma unroll
      for (int mf = 0; mf < 2; ++mf)
        #pragma unroll
        for (int ks = 0; ks < 4; ++ks)
          acc[mf] = __builtin_amdgcn_mfma_f32_16x16x32_bf16(
              af[mf][ks], bW1a[nj][ks], acc[mf], 0, 0, 0);
      const float bias = bias1v[ni];
      #pragma unroll
      for (int mf = 0; mf < 2; ++mf)
        #pragma unroll
        for (int r = 0; r < 4; ++r) {
          const int row = mf * 16 + quad * 4 + r;
          bufH[(row * 64 + ((n >> 3) ^ (row & 15))) * 8 + (n & 7)] =
              f2b(fmaxf(acc[mf][r] + bias, 0.f));
        }
    }
    // half 1: ni = 2,3 — issue loads, compute
    short8 bW1b[2][4];
    #pragma unroll
    for (int nj = 0; nj < 2; ++nj) {
      const int n = (npar + (2 + nj) * 8) * 16 + l15;
      const uint16_t* bp = wb + BOFF_W1T + n * 128 + quad * 8;
      #pragma unroll
      for (int ks = 0; ks < 4; ++ks)
        bW1b[nj][ks] = *(const short8*)(bp + ks * 32);
    }
    #pragma unroll
    for (int nj = 0; nj < 2; ++nj) {
      const int ni = 2 + nj;
      const int n = (npar + ni * 8) * 16 + l15;
      float4v acc[2] = {{0.f, 0.f, 0.f, 0.f}, {0.f, 0.f, 0.f, 0.f}};
      #pragma unroll
      for (int mf = 0; mf < 2; ++mf)
        #pragma unroll
        for (int ks = 0; ks < 4; ++ks)
          acc[mf] = __builtin_amdgcn_mfma_f32_16x16x32_bf16(
              af[mf][ks], bW1b[nj][ks], acc[mf], 0, 0, 0);
      const float bias = bias1v[ni];
      #pragma unroll
      for (int mf = 0; mf < 2; ++mf)
        #pragma unroll
        for (int r = 0; r < 4; ++r) {
          const int row = mf * 16 + quad * 4 + r;
          bufH[(row * 64 + ((n >> 3) ^ (row & 15))) * 8 + (n & 7)] =
              f2b(fmaxf(acc[mf][r] + bias, 0.f));
        }
    }
    // issue GEMM2 half0 B-loads BEFORE the barrier (stay in flight)
    {
      const uint16_t* bp = wb + BOFF_W2T + nG * 512 + quad * 8;
      #pragma unroll
      for (int k8 = 0; k8 < 8; ++k8)
        bB2a[k8] = *(const short8*)(bp + k8 * 32);
    }
  }
  bar_lds();

  short8 bW3[4];                         // GEMM3 weights (cross-barrier)

  // ---- GEMM2: R = smid + H x W2 + b2  (N=128, K=512) ----
  {
    const uint16_t* bp = wb + BOFF_W2T + nG * 512 + quad * 8;
    float4v acc0 = {0.f, 0.f, 0.f, 0.f};
    float4v acc1 = {0.f, 0.f, 0.f, 0.f};
    // half 0 (k = 0..7), weights already in flight
    #pragma unroll
    for (int qtr = 0; qtr < 2; ++qtr) {
      short8 a0[4], a1[4];
      #pragma unroll
      for (int k4 = 0; k4 < 4; ++k4) {
        const int ks = qtr * 4 + k4;
        a0[k4] = *(const short8*)&bufH[(l15 * 64 + ((ks * 4 + quad) ^ l15)) * 8];
        a1[k4] = *(const short8*)&bufH[((16 + l15) * 64 +
                                       ((ks * 4 + quad) ^ l15)) * 8];
      }
      #pragma unroll
      for (int k4 = 0; k4 < 4; ++k4) {
        acc0 = __builtin_amdgcn_mfma_f32_16x16x32_bf16(
            a0[k4], bB2a[qtr * 4 + k4], acc0, 0, 0, 0);
        acc1 = __builtin_amdgcn_mfma_f32_16x16x32_bf16(
            a1[k4], bB2a[qtr * 4 + k4], acc1, 0, 0, 0);
      }
    }
    // half 1 (k = 8..15): issue loads, compute
    short8 bB2b[8];
    #pragma unroll
    for (int k8 = 0; k8 < 8; ++k8)
      bB2b[k8] = *(const short8*)(bp + (8 + k8) * 32);
    #pragma unroll
    for (int qtr = 0; qtr < 2; ++qtr) {
      short8 a0[4], a1[4];
      #pragma unroll
      for (int k4 = 0; k4 < 4; ++k4) {
        const int ks = 8 + qtr * 4 + k4;
        a0[k4] = *(const short8*)&bufH[(l15 * 64 + ((ks * 4 + quad) ^ l15)) * 8];
        a1[k4] = *(const short8*)&bufH[((16 + l15) * 64 +
                                       ((ks * 4 + quad) ^ l15)) * 8];
      }
      #pragma unroll
      for (int k4 = 0; k4 < 4; ++k4) {
        acc0 = __builtin_amdgcn_mfma_f32_16x16x32_bf16(
            a0[k4], bB2b[qtr * 4 + k4], acc0, 0, 0, 0);
        acc1 = __builtin_amdgcn_mfma_f32_16x16x32_bf16(
            a1[k4], bB2b[qtr * 4 + k4], acc1, 0, 0, 0);
      }
    }
    // issue GEMM3 B-loads BEFORE the stores + barrier (stay in flight)
    {
      const uint16_t* bp3 = wb + BOFF_WUP + nG * 128 + quad * 8;
      #pragma unroll
      for (int ks = 0; ks < 4; ++ks)
        bW3[ks] = *(const short8*)(bp3 + ks * 32);
    }
    #pragma unroll
    for (int r = 0; r < 4; ++r) {
      const int row0 = quad * 4 + r;
      const int row1 = 16 + quad * 4 + r;
      bufZ[(row0 * 16 + ((nG >> 3) ^ (row0 & 15))) * 8 + (nG & 7)] =
          f2b(acc0[r] + bias2 + smid[0][r]);
      bufZ[(row1 * 16 + ((nG >> 3) ^ (row1 & 15))) * 8 + (nG & 7)] =
          f2b(acc1[r] + bias2 + smid[1][r]);
    }
  }
  bar_lds();

  // ---- GEMM3: logits = R x WUP^T -> DENSE table store (L2-resident) ----
  {
    short8 ar[2][4];
    #pragma unroll
    for (int mf = 0; mf < 2; ++mf)
      #pragma unroll
      for (int ks = 0; ks < 4; ++ks)
        ar[mf][ks] = *(const short8*)&bufZ[((mf * 16 + l15) * 16 +
                                           ((ks * 4 + quad) ^ l15)) * 8];
    float4v acc[2] = {{0.f, 0.f, 0.f, 0.f}, {0.f, 0.f, 0.f, 0.f}};
    #pragma unroll
    for (int mf = 0; mf < 2; ++mf)
      #pragma unroll
      for (int ks = 0; ks < 4; ++ks)
        acc[mf] = __builtin_amdgcn_mfma_f32_16x16x32_bf16(ar[mf][ks], bW3[ks],
                                                          acc[mf], 0, 0, 0);
    if (nG < NVOCAB) {
      #pragma unroll
      for (int mf = 0; mf < 2; ++mf)
        #pragma unroll
        for (int r = 0; r < 4; ++r) {
          const int row = mf * 16 + quad * 4 + r;
          const int pair = blk * PAIRS_PB + (row >> 1);
          if (pair < NPAIR)
            table[pair * 226 + (row & 1) * 113 + nG] = acc[mf][r];
        }
    }
  }
  #undef ROW_OF
}

// ---------------- K3: gather — random L2 table reads, DENSE out writes -----
__global__ void gather_kernel(const uint32_t* __restrict__ x_raw,
                              const f2v* __restrict__ table2,
                              f2v* __restrict__ out2, int total) {
  // per-wave int64 self-detect: int64 tokens -> odd u32s (high words) all 0
  uint32_t xs = x_raw[2 * (threadIdx.x & 63) + 1];
  unsigned long long nz = __ballot(xs != 0u);
  const int is64 = (nz == 0ull);

  const int i = blockIdx.x * 256 + threadIdx.x;
  if (i >= total) return;
  const int b = i / NVOCAB;
  const int j = i - b * NVOCAB;
  int t0, t1;
  if (is64) {
    t0 = (int)x_raw[4 * b];
    t1 = (int)x_raw[4 * b + 2];
  } else {
    t0 = (int)x_raw[2 * b];
    t1 = (int)x_raw[2 * b + 1];
  }
  t0 = min(max(t0, 0), NVOCAB - 1);
  t1 = min(max(t1, 0), NVOCAB - 1);
  const int pair = t0 * NVOCAB + t1;
  f2v v = table2[(size_t)pair * NVOCAB + j];
  __builtin_nontemporal_store(v, &out2[i]);
}

extern "C" void kernel_launch(void* const* d_in, const int* in_sizes, int n_in,
                              void* d_out, int out_size, void* d_ws, size_t ws_size,
                              hipStream_t stream) {
  // ws layout (byte offsets)
  float*    wf        = (float*)((char*)d_ws + 256);             // biases only
  float*    resid_pre = (float*)((char*)d_ws + 905984);
  float*    qt        = (float*)((char*)d_ws + 1021696);
  float*    kt        = (float*)((char*)d_ws + 1137408);
  float*    vt        = (float*)((char*)d_ws + 1253120);
  float*    table     = (float*)((char*)d_ws + 1368832);         // 11543176 B
  uint16_t* wb        = (uint16_t*)((char*)d_ws + 12912016);     // 327680 B

  const int B = in_sizes[0] / 2;

  SrcPtrs sp;
  for (int i = 0; i < 11; ++i) sp.p[i] = d_in[i + 1];

  // 226 qkv + 427 wb + 2 bias = 655 blocks
  build_kernel<<<655, 384, 0, stream>>>(sp, wf, resid_pre, qt, kt, vt, wb);

  const int nblk = (NPAIR + PAIRS_PB - 1) / PAIRS_PB;  // 799
  pair_mfma_kernel<<<nblk, 512, 0, stream>>>(resid_pre, qt, kt, vt, wf, wb,
                                             table);

  const int total = B * NVOCAB;   // float2 elements of out
  gather_kernel<<<(total + 255) / 256, 256, 0, stream>>>(
      (const uint32_t*)d_in[0], (const f2v*)table, (f2v*)d_out, total);
}

// Round 9
// 243.799 us; speedup vs baseline: 1.0006x; 1.0006x over previous
//
#include <hip/hip_runtime.h>
#include <hip/hip_bf16.h>
#include <stdint.h>

typedef __hip_bfloat16 bf16;
typedef __attribute__((ext_vector_type(8))) short short8;
typedef __attribute__((ext_vector_type(4))) float float4v;
typedef __attribute__((ext_vector_type(2))) float f2v;

#define NVOCAB 113
#define NPAIR (113 * 113)   // 12769
#define DDIM 128
#define HIDDIM 512
#define PAIRS_PB 16         // pairs per block
#define ROWS_PB 32          // rows per block

// fp32 pool element offsets (only biases used)
#define OFF_B1  145792
#define OFF_B2  211840

// bf16 transposed weight pool wb (element offsets)
#define BOFF_WOT 0                         // WOT[d][hk] = W_O[hk][d]     128x128
#define BOFF_W1T 16384                     // W1T[n][d]  = W1[d][n]       512x128
#define BOFF_W2T (16384 + 65536)           // W2T[d][j]  = W2[j][d]       128x512
#define BOFF_WUP (16384 + 65536 + 65536)   // WUP[v][d]  = W_U[v][d]|0    128x128
#define BTOTAL   (16384 + 65536 + 65536 + 16384)  // 163840

__device__ __forceinline__ uint16_t f2b(float f) {
  bf16 h = __float2bfloat16(f);
  return *(uint16_t*)&h;
}
__device__ __forceinline__ float b2f(uint16_t u) {
  return __uint_as_float(((uint32_t)u) << 16);
}
__device__ __forceinline__ float ldsrc(const void* p, int i, int isb) {
  return isb ? b2f(((const uint16_t*)p)[i]) : ((const float*)p)[i];
}

// LDS-only barrier: waits ds ops but leaves global loads in flight.
__device__ __forceinline__ void bar_lds() {
  asm volatile("s_waitcnt lgkmcnt(0)\n\ts_barrier" ::: "memory");
}

// Inline-asm 16B weight load: output register is defined HERE — the
// compiler cannot sink it to the use site / re-serialize the batch.
__device__ __forceinline__ short8 gl16(const uint16_t* p) {
  short8 r;
  asm volatile("global_load_dwordx4 %0, %1, off" : "=v"(r) : "v"(p));
  return r;
}
// Dependency-carrying waits: consumers of the operands are ordered after
// the s_waitcnt via the register data dependency (rule-18-safe).
#define VMW4(a0,a1,a2,a3) \
  asm volatile("s_waitcnt vmcnt(0)" : "+v"(a0),"+v"(a1),"+v"(a2),"+v"(a3))
#define VMW8(a0,a1,a2,a3,a4,a5,a6,a7) \
  asm volatile("s_waitcnt vmcnt(0)" : "+v"(a0),"+v"(a1),"+v"(a2),"+v"(a3), \
                                      "+v"(a4),"+v"(a5),"+v"(a6),"+v"(a7))

// per-wave dtype self-detection: 64 samples of tok_emb raw u32s.
__device__ __forceinline__ int detect_isb(const uint32_t* __restrict__ tok_raw) {
  uint32_t u = tok_raw[threadIdx.x & 63];
  int e = (u >> 7) & 0xff;
  unsigned long long m = __ballot(e >= 100 && e <= 126);
  return __popcll(m) >= 48;
}

struct SrcPtrs { const void* p[11]; };
// p[0]=tok p[1]=pos p[2]=WQ p[3]=WK p[4]=WV p[5]=WO p[6]=W1 p[7]=b1 p[8]=W2 p[9]=b2 p[10]=WU

// ---------------- K1: all prep in one launch, sources read directly --------
__global__ void __launch_bounds__(384) build_kernel(
    SrcPtrs sp, float* __restrict__ wf,
    float* __restrict__ resid_pre, float* __restrict__ qt,
    float* __restrict__ kt, float* __restrict__ vt,
    uint16_t* __restrict__ wb) {
  const int tid = threadIdx.x;
  const int blk = blockIdx.x;
  const int isb = detect_isb((const uint32_t*)sp.p[0]);

  if (blk < 226) {
    // ---- qkv + resid ----
    const int row = blk;
    const int t = row >> 1, p = row & 1;
    __shared__ float r[DDIM];
    if (tid < DDIM) {
      float rv = ldsrc(sp.p[0], t * DDIM + tid, isb) +
                 ldsrc(sp.p[1], p * DDIM + tid, isb);
      r[tid] = rv;
      resid_pre[row * DDIM + tid] = rv;
    }
    __syncthreads();
    const int which = tid >> 7, jj = tid & 127;
    const int h = jj >> 5, j = jj & 31;
    const void* wsrc = sp.p[2 + which];
    const int base = h * 4096 + j;
    float a = 0.f;
    if (isb) {
      const uint16_t* w16 = (const uint16_t*)wsrc;
      #pragma unroll 8
      for (int d = 0; d < 128; ++d)
        a += r[d] * b2f(w16[base + d * 32]);
    } else {
      const float* w32 = (const float*)wsrc;
      #pragma unroll 8
      for (int d = 0; d < 128; ++d)
        a += r[d] * w32[base + d * 32];
    }
    float* outp = (which == 0) ? qt : (which == 1) ? kt : vt;
    outp[row * DDIM + jj] = a;
  } else if (blk < 653) {
    // ---- wb build ----
    const int idx = (blk - 226) * 384 + tid;
    if (idx < BTOTAL) {
      float v;
      if (idx < BOFF_W1T) {                       // WOT[d][c] = W_O[c*128+d]
        int l = idx, d = l >> 7, c = l & 127;
        v = ldsrc(sp.p[5], c * 128 + d, isb);
      } else if (idx < BOFF_W2T) {                // W1T[n][d] = W1[d*512+n]
        int l = idx - BOFF_W1T, n = l >> 7, d = l & 127;
        v = ldsrc(sp.p[6], d * 512 + n, isb);
      } else if (idx < BOFF_WUP) {                // W2T[d][j] = W2[j*128+d]
        int l = idx - BOFF_W2T, d = l >> 9, j = l & 511;
        v = ldsrc(sp.p[8], j * 128 + d, isb);
      } else {                                    // WUP[v][d] = W_U[v*128+d] or 0
        int l = idx - BOFF_WUP, vv = l >> 7, d = l & 127;
        v = (vv < NVOCAB) ? ldsrc(sp.p[10], vv * 128 + d, isb) : 0.f;
      }
      wb[idx] = f2b(v);
    }
  } else {
    // ---- biases ----
    const int i = (blk - 653) * 384 + tid;
    if (i < 512) wf[OFF_B1 + i] = ldsrc(sp.p[7], i, isb);
    else if (i < 640) wf[OFF_B2 + (i - 512)] = ldsrc(sp.p[9], i - 512, isb);
  }
}

// ---------------- K2: fused MFMA kernel, 16 pairs (32 rows) / block -------
// Weight loads are inline-asm batches (compiler cannot re-serialize);
// exactly one vmcnt(0) wait per GEMM phase, issued-early / waited-late.
// MFMA accumulation order identical to R4-R8 -> bit-identical output.
__global__ void __launch_bounds__(512, 2) pair_mfma_kernel(
    const float* __restrict__ resid_pre, const float* __restrict__ qt,
    const float* __restrict__ kt, const float* __restrict__ vt,
    const float* __restrict__ wf, const uint16_t* __restrict__ wb,
    float* __restrict__ table) {
  __shared__ uint16_t bufH[ROWS_PB * 512];   // 32 KB (H staging)
  __shared__ uint16_t bufZ[ROWS_PB * 128];   // 8 KB (Z, then R)
  __shared__ uint16_t bufS[ROWS_PB * 128];   // 8 KB (smid bf16)
  __shared__ float    spat[PAIRS_PB * 16];

  const int tid = threadIdx.x;
  const int blk = blockIdx.x;
  const int lane = tid & 63;
  const int npar = tid >> 6;            // wave id 0..7
  const int l15 = lane & 15, quad = lane >> 4;

  #define ROW_OF(row_) ({                                        \
    int pr_ = blk * PAIRS_PB + ((row_) >> 1);                    \
    if (pr_ >= NPAIR) pr_ = NPAIR - 1;                           \
    int t0_ = pr_ / NVOCAB, t1_ = pr_ - t0_ * NVOCAB;            \
    ((row_) & 1) ? t1_ * 2 + 1 : t0_ * 2; })

  const int nG = npar * 16 + l15;       // N=128 column for GEMM0/2/3

  // ---- issue GEMM0 weights at the very top (fly through whole prologue) --
  short8 bW0[4];
  {
    const uint16_t* bp = wb + BOFF_WOT + nG * 128 + quad * 8;
    bW0[0] = gl16(bp);       bW0[1] = gl16(bp + 32);
    bW0[2] = gl16(bp + 64);  bW0[3] = gl16(bp + 96);
  }

  float rpre[2][4];
  #pragma unroll
  for (int mf = 0; mf < 2; ++mf)
    #pragma unroll
    for (int r = 0; r < 4; ++r)
      rpre[mf][r] = resid_pre[ROW_OF(mf * 16 + quad * 4 + r) * DDIM + nG];
  float bias1v[4];
  #pragma unroll
  for (int ni = 0; ni < 4; ++ni)
    bias1v[ni] = wf[OFF_B1 + (npar + ni * 8) * 16 + l15];
  const float bias2 = wf[OFF_B2 + nG];
  // vt rows for the Z phase: 2 rows x 8 cols
  const int zm = tid >> 4, zc0 = (tid & 15) * 8;
  float4 zv0a, zv0b, zv1a, zv1b;
  {
    const int zr0 = ROW_OF((zm >> 1) * 2);
    const int zr1 = ROW_OF((zm >> 1) * 2 + 1);
    const float4* p0 = (const float4*)(vt + zr0 * DDIM + zc0);
    const float4* p1 = (const float4*)(vt + zr1 * DDIM + zc0);
    zv0a = p0[0]; zv0b = p0[1]; zv1a = p1[0]; zv1b = p1[1];
  }

  // ---- fused scores + softmax + blend (128 threads) ----
  if (tid < 128) {
    const int pl = tid >> 3, s = tid & 7;
    int pair = blk * PAIRS_PB + pl;
    if (pair >= NPAIR) pair = NPAIR - 1;           // clamp: results discarded
    const int t0 = pair / NVOCAB, t1 = pair - t0 * NVOCAB;
    const int row0 = t0 * 2, row1 = t1 * 2 + 1;
    const int h = s >> 1, qp = s & 1;
    const float4* qrow = (const float4*)(qt + (qp ? row1 : row0) * DDIM + h * 32);
    const float4* k0r  = (const float4*)(kt + row0 * DDIM + h * 32);
    const float4* k1r  = (const float4*)(kt + row1 * DDIM + h * 32);
    float acc0 = 0.f, acc1 = 0.f;
    #pragma unroll
    for (int j = 0; j < 8; ++j) {
      float4 qv = qrow[j], kv0 = k0r[j], kv1 = k1r[j];
      acc0 += qv.x * kv0.x + qv.y * kv0.y + qv.z * kv0.z + qv.w * kv0.w;
      acc1 += qv.x * kv1.x + qv.y * kv1.y + qv.z * kv1.z + qv.w * kv1.w;
    }
    float s0 = acc0 * 0.17677669529663687f;
    float s1 = acc1 * 0.17677669529663687f;
    float m = fmaxf(s0, s1);
    float e0 = __expf(s0 - m), e1 = __expf(s1 - m);
    float inv = 1.f / (e0 + e1);
    spat[pl * 16 + s * 2]     = 0.5f + 0.5f * e0 * inv;
    spat[pl * 16 + s * 2 + 1] = 0.5f + 0.5f * e1 * inv;
  }
  bar_lds();

  // ---- Z = pattern-weighted V (prefetched), staged bf16 ----
  {
    const int pl = zm >> 1, qp = zm & 1;
    const int h = zc0 >> 5;
    const float p0 = spat[pl * 16 + h * 4 + qp * 2];
    const float p1 = spat[pl * 16 + h * 4 + qp * 2 + 1];
    float v0[8] = {zv0a.x, zv0a.y, zv0a.z, zv0a.w, zv0b.x, zv0b.y, zv0b.z, zv0b.w};
    float v1[8] = {zv1a.x, zv1a.y, zv1a.z, zv1a.w, zv1b.x, zv1b.y, zv1b.z, zv1b.w};
    short8 pk;
    #pragma unroll
    for (int e = 0; e < 8; ++e)
      pk[e] = (short)f2b(p0 * v0[e] + p1 * v1[e]);
    *(short8*)&bufZ[(zm * 16 + ((zc0 >> 3) ^ (zm & 15))) * 8] = pk;
  }
  bar_lds();

  float smid[2][4];
  short8 bW1[4][4];                      // GEMM1 weights (issued in GEMM0)

  // ---- GEMM0: smid = Z x WOT + resid  (N=128, K=128) ----
  {
    short8 af[2][4];
    #pragma unroll
    for (int mf = 0; mf < 2; ++mf)
      #pragma unroll
      for (int ks = 0; ks < 4; ++ks)
        af[mf][ks] = *(const short8*)&bufZ[((mf * 16 + l15) * 16 +
                                           ((ks * 4 + quad) ^ l15)) * 8];
    // gate GEMM0 weights, then immediately issue GEMM1's 16 loads
    VMW4(bW0[0], bW0[1], bW0[2], bW0[3]);
    #pragma unroll
    for (int ni = 0; ni < 4; ++ni) {
      const int n = (npar + ni * 8) * 16 + l15;
      const uint16_t* bp = wb + BOFF_W1T + n * 128 + quad * 8;
      #pragma unroll
      for (int ks = 0; ks < 4; ++ks)
        bW1[ni][ks] = gl16(bp + ks * 32);
    }
    float4v acc[2] = {{0.f, 0.f, 0.f, 0.f}, {0.f, 0.f, 0.f, 0.f}};
    #pragma unroll
    for (int mf = 0; mf < 2; ++mf)
      #pragma unroll
      for (int ks = 0; ks < 4; ++ks)
        acc[mf] = __builtin_amdgcn_mfma_f32_16x16x32_bf16(af[mf][ks], bW0[ks],
                                                          acc[mf], 0, 0, 0);
    #pragma unroll
    for (int mf = 0; mf < 2; ++mf)
      #pragma unroll
      for (int r = 0; r < 4; ++r) {
        const int row = mf * 16 + quad * 4 + r;
        float v = acc[mf][r] + rpre[mf][r];
        smid[mf][r] = v;
        bufS[(row * 16 + ((nG >> 3) ^ (row & 15))) * 8 + (nG & 7)] = f2b(v);
      }
  }
  bar_lds();

  short8 bB2[16];                        // GEMM2 weights (issued in GEMM1)

  // ---- GEMM1: H = relu(smid x W1 + b1)  (N=512, K=128) ----
  {
    short8 af[2][4];
    #pragma unroll
    for (int mf = 0; mf < 2; ++mf)
      #pragma unroll
      for (int ks = 0; ks < 4; ++ks)
        af[mf][ks] = *(const short8*)&bufS[((mf * 16 + l15) * 16 +
                                           ((ks * 4 + quad) ^ l15)) * 8];
    // gate GEMM1 weights, then issue GEMM2's 16 loads
    VMW8(bW1[0][0], bW1[0][1], bW1[0][2], bW1[0][3],
         bW1[1][0], bW1[1][1], bW1[1][2], bW1[1][3]);
    VMW8(bW1[2][0], bW1[2][1], bW1[2][2], bW1[2][3],
         bW1[3][0], bW1[3][1], bW1[3][2], bW1[3][3]);
    {
      const uint16_t* bp = wb + BOFF_W2T + nG * 512 + quad * 8;
      #pragma unroll
      for (int k8 = 0; k8 < 16; ++k8)
        bB2[k8] = gl16(bp + k8 * 32);
    }
    #pragma unroll
    for (int ni = 0; ni < 4; ++ni) {
      const int n = (npar + ni * 8) * 16 + l15;
      float4v acc[2] = {{0.f, 0.f, 0.f, 0.f}, {0.f, 0.f, 0.f, 0.f}};
      #pragma unroll
      for (int mf = 0; mf < 2; ++mf)
        #pragma unroll
        for (int ks = 0; ks < 4; ++ks)
          acc[mf] = __builtin_amdgcn_mfma_f32_16x16x32_bf16(
              af[mf][ks], bW1[ni][ks], acc[mf], 0, 0, 0);
      const float bias = bias1v[ni];
      #pragma unroll
      for (int mf = 0; mf < 2; ++mf)
        #pragma unroll
        for (int r = 0; r < 4; ++r) {
          const int row = mf * 16 + quad * 4 + r;
          bufH[(row * 64 + ((n >> 3) ^ (row & 15))) * 8 + (n & 7)] =
              f2b(fmaxf(acc[mf][r] + bias, 0.f));
        }
    }
  }
  bar_lds();

  short8 bW3[4];                         // GEMM3 weights (issued in GEMM2)

  // ---- GEMM2: R = smid + H x W2 + b2  (N=128, K=512) ----
  {
    // gate GEMM2 weights, then issue GEMM3's 4 loads
    VMW8(bB2[0], bB2[1], bB2[2],  bB2[3],  bB2[4],  bB2[5],  bB2[6],  bB2[7]);
    VMW8(bB2[8], bB2[9], bB2[10], bB2[11], bB2[12], bB2[13], bB2[14], bB2[15]);
    {
      const uint16_t* bp3 = wb + BOFF_WUP + nG * 128 + quad * 8;
      bW3[0] = gl16(bp3);       bW3[1] = gl16(bp3 + 32);
      bW3[2] = gl16(bp3 + 64);  bW3[3] = gl16(bp3 + 96);
    }
    float4v acc0 = {0.f, 0.f, 0.f, 0.f};
    float4v acc1 = {0.f, 0.f, 0.f, 0.f};
    #pragma unroll
    for (int half = 0; half < 2; ++half) {
      #pragma unroll
      for (int qtr = 0; qtr < 2; ++qtr) {
        short8 a0[4], a1[4];
        #pragma unroll
        for (int k4 = 0; k4 < 4; ++k4) {
          const int ks = half * 8 + qtr * 4 + k4;
          a0[k4] = *(const short8*)&bufH[(l15 * 64 +
                                         ((ks * 4 + quad) ^ l15)) * 8];
          a1[k4] = *(const short8*)&bufH[((16 + l15) * 64 +
                                         ((ks * 4 + quad) ^ l15)) * 8];
        }
        #pragma unroll
        for (int k4 = 0; k4 < 4; ++k4) {
          const int ks = half * 8 + qtr * 4 + k4;
          acc0 = __builtin_amdgcn_mfma_f32_16x16x32_bf16(
              a0[k4], bB2[ks], acc0, 0, 0, 0);
          acc1 = __builtin_amdgcn_mfma_f32_16x16x32_bf16(
              a1[k4], bB2[ks], acc1, 0, 0, 0);
        }
      }
    }
    #pragma unroll
    for (int r = 0; r < 4; ++r) {
      const int row0 = quad * 4 + r;
      const int row1 = 16 + quad * 4 + r;
      bufZ[(row0 * 16 + ((nG >> 3) ^ (row0 & 15))) * 8 + (nG & 7)] =
          f2b(acc0[r] + bias2 + smid[0][r]);
      bufZ[(row1 * 16 + ((nG >> 3) ^ (row1 & 15))) * 8 + (nG & 7)] =
          f2b(acc1[r] + bias2 + smid[1][r]);
    }
  }
  bar_lds();

  // ---- GEMM3: logits = R x WUP^T -> DENSE table store (L2-resident) ----
  {
    short8 ar[2][4];
    #pragma unroll
    for (int mf = 0; mf < 2; ++mf)
      #pragma unroll
      for (int ks = 0; ks < 4; ++ks)
        ar[mf][ks] = *(const short8*)&bufZ[((mf * 16 + l15) * 16 +
                                           ((ks * 4 + quad) ^ l15)) * 8];
    VMW4(bW3[0], bW3[1], bW3[2], bW3[3]);
    float4v acc[2] = {{0.f, 0.f, 0.f, 0.f}, {0.f, 0.f, 0.f, 0.f}};
    #pragma unroll
    for (int mf = 0; mf < 2; ++mf)
      #pragma unroll
      for (int ks = 0; ks < 4; ++ks)
        acc[mf] = __builtin_amdgcn_mfma_f32_16x16x32_bf16(ar[mf][ks], bW3[ks],
                                                          acc[mf], 0, 0, 0);
    if (nG < NVOCAB) {
      #pragma unroll
      for (int mf = 0; mf < 2; ++mf)
        #pragma unroll
        for (int r = 0; r < 4; ++r) {
          const int row = mf * 16 + quad * 4 + r;
          const int pair = blk * PAIRS_PB + (row >> 1);
          if (pair < NPAIR)
            table[pair * 226 + (row & 1) * 113 + nG] = acc[mf][r];
        }
    }
  }
  #undef ROW_OF
}

// ---------------- K3: gather — random L2 table reads, DENSE out writes -----
__global__ void gather_kernel(const uint32_t* __restrict__ x_raw,
                              const f2v* __restrict__ table2,
                              f2v* __restrict__ out2, int total) {
  // per-wave int64 self-detect: int64 tokens -> odd u32s (high words) all 0
  uint32_t xs = x_raw[2 * (threadIdx.x & 63) + 1];
  unsigned long long nz = __ballot(xs != 0u);
  const int is64 = (nz == 0ull);

  const int i = blockIdx.x * 256 + threadIdx.x;
  if (i >= total) return;
  const int b = i / NVOCAB;
  const int j = i - b * NVOCAB;
  int t0, t1;
  if (is64) {
    t0 = (int)x_raw[4 * b];
    t1 = (int)x_raw[4 * b + 2];
  } else {
    t0 = (int)x_raw[2 * b];
    t1 = (int)x_raw[2 * b + 1];
  }
  t0 = min(max(t0, 0), NVOCAB - 1);
  t1 = min(max(t1, 0), NVOCAB - 1);
  const int pair = t0 * NVOCAB + t1;
  f2v v = table2[(size_t)pair * NVOCAB + j];
  __builtin_nontemporal_store(v, &out2[i]);
}

extern "C" void kernel_launch(void* const* d_in, const int* in_sizes, int n_in,
                              void* d_out, int out_size, void* d_ws, size_t ws_size,
                              hipStream_t stream) {
  // ws layout (byte offsets)
  float*    wf        = (float*)((char*)d_ws + 256);             // biases only
  float*    resid_pre = (float*)((char*)d_ws + 905984);
  float*    qt        = (float*)((char*)d_ws + 1021696);
  float*    kt        = (float*)((char*)d_ws + 1137408);
  float*    vt        = (float*)((char*)d_ws + 1253120);
  float*    table     = (float*)((char*)d_ws + 1368832);         // 11543176 B
  uint16_t* wb        = (uint16_t*)((char*)d_ws + 12912016);     // 327680 B

  const int B = in_sizes[0] / 2;

  SrcPtrs sp;
  for (int i = 0; i < 11; ++i) sp.p[i] = d_in[i + 1];

  // 226 qkv + 427 wb + 2 bias = 655 blocks
  build_kernel<<<655, 384, 0, stream>>>(sp, wf, resid_pre, qt, kt, vt, wb);

  const int nblk = (NPAIR + PAIRS_PB - 1) / PAIRS_PB;  // 799
  pair_mfma_kernel<<<nblk, 512, 0, stream>>>(resid_pre, qt, kt, vt, wf, wb,
                                             table);

  const int total = B * NVOCAB;   // float2 elements of out
  gather_kernel<<<(total + 255) / 256, 256, 0, stream>>>(
      (const uint32_t*)d_in[0], (const f2v*)table, (f2v*)d_out, total);
}

// Round 10
// 233.507 us; speedup vs baseline: 1.0447x; 1.0441x over previous
//
#include <hip/hip_runtime.h>
#include <hip/hip_bf16.h>
#include <stdint.h>

typedef __hip_bfloat16 bf16;
typedef __attribute__((ext_vector_type(8))) short short8;
typedef __attribute__((ext_vector_type(4))) float float4v;
typedef __attribute__((ext_vector_type(2))) float f2v;

#define NVOCAB 113
#define NPAIR (113 * 113)   // 12769
#define DDIM 128
#define HIDDIM 512
#define PAIRS_PB 16         // pairs per block
#define ROWS_PB 32          // rows per block

// fp32 pool element offsets (only biases used)
#define OFF_B1  145792
#define OFF_B2  211840

// bf16 transposed weight pool wb (element offsets)
#define BOFF_WOT 0                         // WOT[d][hk] = W_O[hk][d]     128x128
#define BOFF_W1T 16384                     // W1T[n][d]  = W1[d][n]       512x128
#define BOFF_W2T (16384 + 65536)           // W2T[d][j]  = W2[j][d]       128x512
#define BOFF_WUP (16384 + 65536 + 65536)   // WUP[v][d]  = W_U[v][d]|0    128x128
#define BTOTAL   (16384 + 65536 + 65536 + 16384)  // 163840

__device__ __forceinline__ uint16_t f2b(float f) {
  bf16 h = __float2bfloat16(f);
  return *(uint16_t*)&h;
}
__device__ __forceinline__ float b2f(uint16_t u) {
  return __uint_as_float(((uint32_t)u) << 16);
}
__device__ __forceinline__ float ldsrc(const void* p, int i, int isb) {
  return isb ? b2f(((const uint16_t*)p)[i]) : ((const float*)p)[i];
}

// LDS-only barrier: waits ds ops but leaves global loads in flight.
__device__ __forceinline__ void bar_lds() {
  asm volatile("s_waitcnt lgkmcnt(0)\n\ts_barrier" ::: "memory");
}

// Inline-asm 16B weight load: output register is defined HERE — the
// compiler cannot sink it to the use site / re-serialize the batch.
__device__ __forceinline__ short8 gl16(const uint16_t* p) {
  short8 r;
  asm volatile("global_load_dwordx4 %0, %1, off" : "=v"(r) : "v"(p));
  return r;
}
// Dependency-carrying waits: consumers of the operands are ordered after
// the s_waitcnt via the register data dependency (rule-18-safe).
#define VMW4(a0,a1,a2,a3) \
  asm volatile("s_waitcnt vmcnt(0)" : "+v"(a0),"+v"(a1),"+v"(a2),"+v"(a3))
#define VMW8(a0,a1,a2,a3,a4,a5,a6,a7) \
  asm volatile("s_waitcnt vmcnt(0)" : "+v"(a0),"+v"(a1),"+v"(a2),"+v"(a3), \
                                      "+v"(a4),"+v"(a5),"+v"(a6),"+v"(a7))

// per-wave dtype self-detection: 64 samples of tok_emb raw u32s.
__device__ __forceinline__ int detect_isb(const uint32_t* __restrict__ tok_raw) {
  uint32_t u = tok_raw[threadIdx.x & 63];
  int e = (u >> 7) & 0xff;
  unsigned long long m = __ballot(e >= 100 && e <= 126);
  return __popcll(m) >= 48;
}

struct SrcPtrs { const void* p[11]; };
// p[0]=tok p[1]=pos p[2]=WQ p[3]=WK p[4]=WV p[5]=WO p[6]=W1 p[7]=b1 p[8]=W2 p[9]=b2 p[10]=WU

// ---------------- K1: all prep in one launch, sources read directly --------
__global__ void __launch_bounds__(384) build_kernel(
    SrcPtrs sp, float* __restrict__ wf,
    float* __restrict__ resid_pre, float* __restrict__ qt,
    float* __restrict__ kt, float* __restrict__ vt,
    uint16_t* __restrict__ wb) {
  const int tid = threadIdx.x;
  const int blk = blockIdx.x;
  const int isb = detect_isb((const uint32_t*)sp.p[0]);

  if (blk < 226) {
    // ---- qkv + resid ----
    const int row = blk;
    const int t = row >> 1, p = row & 1;
    __shared__ float r[DDIM];
    if (tid < DDIM) {
      float rv = ldsrc(sp.p[0], t * DDIM + tid, isb) +
                 ldsrc(sp.p[1], p * DDIM + tid, isb);
      r[tid] = rv;
      resid_pre[row * DDIM + tid] = rv;
    }
    __syncthreads();
    const int which = tid >> 7, jj = tid & 127;
    const int h = jj >> 5, j = jj & 31;
    const void* wsrc = sp.p[2 + which];
    const int base = h * 4096 + j;
    float a = 0.f;
    if (isb) {
      const uint16_t* w16 = (const uint16_t*)wsrc;
      #pragma unroll 8
      for (int d = 0; d < 128; ++d)
        a += r[d] * b2f(w16[base + d * 32]);
    } else {
      const float* w32 = (const float*)wsrc;
      #pragma unroll 8
      for (int d = 0; d < 128; ++d)
        a += r[d] * w32[base + d * 32];
    }
    float* outp = (which == 0) ? qt : (which == 1) ? kt : vt;
    outp[row * DDIM + jj] = a;
  } else if (blk < 653) {
    // ---- wb build ----
    const int idx = (blk - 226) * 384 + tid;
    if (idx < BTOTAL) {
      float v;
      if (idx < BOFF_W1T) {                       // WOT[d][c] = W_O[c*128+d]
        int l = idx, d = l >> 7, c = l & 127;
        v = ldsrc(sp.p[5], c * 128 + d, isb);
      } else if (idx < BOFF_W2T) {                // W1T[n][d] = W1[d*512+n]
        int l = idx - BOFF_W1T, n = l >> 7, d = l & 127;
        v = ldsrc(sp.p[6], d * 512 + n, isb);
      } else if (idx < BOFF_WUP) {                // W2T[d][j] = W2[j*128+d]
        int l = idx - BOFF_W2T, d = l >> 9, j = l & 511;
        v = ldsrc(sp.p[8], j * 128 + d, isb);
      } else {                                    // WUP[v][d] = W_U[v*128+d] or 0
        int l = idx - BOFF_WUP, vv = l >> 7, d = l & 127;
        v = (vv < NVOCAB) ? ldsrc(sp.p[10], vv * 128 + d, isb) : 0.f;
      }
      wb[idx] = f2b(v);
    }
  } else {
    // ---- biases ----
    const int i = (blk - 653) * 384 + tid;
    if (i < 512) wf[OFF_B1 + i] = ldsrc(sp.p[7], i, isb);
    else if (i < 640) wf[OFF_B2 + (i - 512)] = ldsrc(sp.p[9], i - 512, isb);
  }
}

// ---------------- K2: fused MFMA kernel, 16 pairs (32 rows) / block -------
// (byte-identical compute to R9; bit-identical output)
__global__ void __launch_bounds__(512, 2) pair_mfma_kernel(
    const float* __restrict__ resid_pre, const float* __restrict__ qt,
    const float* __restrict__ kt, const float* __restrict__ vt,
    const float* __restrict__ wf, const uint16_t* __restrict__ wb,
    float* __restrict__ table) {
  __shared__ uint16_t bufH[ROWS_PB * 512];   // 32 KB (H staging)
  __shared__ uint16_t bufZ[ROWS_PB * 128];   // 8 KB (Z, then R)
  __shared__ uint16_t bufS[ROWS_PB * 128];   // 8 KB (smid bf16)
  __shared__ float    spat[PAIRS_PB * 16];

  const int tid = threadIdx.x;
  const int blk = blockIdx.x;
  const int lane = tid & 63;
  const int npar = tid >> 6;            // wave id 0..7
  const int l15 = lane & 15, quad = lane >> 4;

  #define ROW_OF(row_) ({                                        \
    int pr_ = blk * PAIRS_PB + ((row_) >> 1);                    \
    if (pr_ >= NPAIR) pr_ = NPAIR - 1;                           \
    int t0_ = pr_ / NVOCAB, t1_ = pr_ - t0_ * NVOCAB;            \
    ((row_) & 1) ? t1_ * 2 + 1 : t0_ * 2; })

  const int nG = npar * 16 + l15;       // N=128 column for GEMM0/2/3

  // ---- issue GEMM0 weights at the very top (fly through whole prologue) --
  short8 bW0[4];
  {
    const uint16_t* bp = wb + BOFF_WOT + nG * 128 + quad * 8;
    bW0[0] = gl16(bp);       bW0[1] = gl16(bp + 32);
    bW0[2] = gl16(bp + 64);  bW0[3] = gl16(bp + 96);
  }

  float rpre[2][4];
  #pragma unroll
  for (int mf = 0; mf < 2; ++mf)
    #pragma unroll
    for (int r = 0; r < 4; ++r)
      rpre[mf][r] = resid_pre[ROW_OF(mf * 16 + quad * 4 + r) * DDIM + nG];
  float bias1v[4];
  #pragma unroll
  for (int ni = 0; ni < 4; ++ni)
    bias1v[ni] = wf[OFF_B1 + (npar + ni * 8) * 16 + l15];
  const float bias2 = wf[OFF_B2 + nG];
  // vt rows for the Z phase: 2 rows x 8 cols
  const int zm = tid >> 4, zc0 = (tid & 15) * 8;
  float4 zv0a, zv0b, zv1a, zv1b;
  {
    const int zr0 = ROW_OF((zm >> 1) * 2);
    const int zr1 = ROW_OF((zm >> 1) * 2 + 1);
    const float4* p0 = (const float4*)(vt + zr0 * DDIM + zc0);
    const float4* p1 = (const float4*)(vt + zr1 * DDIM + zc0);
    zv0a = p0[0]; zv0b = p0[1]; zv1a = p1[0]; zv1b = p1[1];
  }

  // ---- fused scores + softmax + blend (128 threads) ----
  if (tid < 128) {
    const int pl = tid >> 3, s = tid & 7;
    int pair = blk * PAIRS_PB + pl;
    if (pair >= NPAIR) pair = NPAIR - 1;           // clamp: results discarded
    const int t0 = pair / NVOCAB, t1 = pair - t0 * NVOCAB;
    const int row0 = t0 * 2, row1 = t1 * 2 + 1;
    const int h = s >> 1, qp = s & 1;
    const float4* qrow = (const float4*)(qt + (qp ? row1 : row0) * DDIM + h * 32);
    const float4* k0r  = (const float4*)(kt + row0 * DDIM + h * 32);
    const float4* k1r  = (const float4*)(kt + row1 * DDIM + h * 32);
    float acc0 = 0.f, acc1 = 0.f;
    #pragma unroll
    for (int j = 0; j < 8; ++j) {
      float4 qv = qrow[j], kv0 = k0r[j], kv1 = k1r[j];
      acc0 += qv.x * kv0.x + qv.y * kv0.y + qv.z * kv0.z + qv.w * kv0.w;
      acc1 += qv.x * kv1.x + qv.y * kv1.y + qv.z * kv1.z + qv.w * kv1.w;
    }
    float s0 = acc0 * 0.17677669529663687f;
    float s1 = acc1 * 0.17677669529663687f;
    float m = fmaxf(s0, s1);
    float e0 = __expf(s0 - m), e1 = __expf(s1 - m);
    float inv = 1.f / (e0 + e1);
    spat[pl * 16 + s * 2]     = 0.5f + 0.5f * e0 * inv;
    spat[pl * 16 + s * 2 + 1] = 0.5f + 0.5f * e1 * inv;
  }
  bar_lds();

  // ---- Z = pattern-weighted V (prefetched), staged bf16 ----
  {
    const int pl = zm >> 1, qp = zm & 1;
    const int h = zc0 >> 5;
    const float p0 = spat[pl * 16 + h * 4 + qp * 2];
    const float p1 = spat[pl * 16 + h * 4 + qp * 2 + 1];
    float v0[8] = {zv0a.x, zv0a.y, zv0a.z, zv0a.w, zv0b.x, zv0b.y, zv0b.z, zv0b.w};
    float v1[8] = {zv1a.x, zv1a.y, zv1a.z, zv1a.w, zv1b.x, zv1b.y, zv1b.z, zv1b.w};
    short8 pk;
    #pragma unroll
    for (int e = 0; e < 8; ++e)
      pk[e] = (short)f2b(p0 * v0[e] + p1 * v1[e]);
    *(short8*)&bufZ[(zm * 16 + ((zc0 >> 3) ^ (zm & 15))) * 8] = pk;
  }
  bar_lds();

  float smid[2][4];
  short8 bW1[4][4];                      // GEMM1 weights (issued in GEMM0)

  // ---- GEMM0: smid = Z x WOT + resid  (N=128, K=128) ----
  {
    short8 af[2][4];
    #pragma unroll
    for (int mf = 0; mf < 2; ++mf)
      #pragma unroll
      for (int ks = 0; ks < 4; ++ks)
        af[mf][ks] = *(const short8*)&bufZ[((mf * 16 + l15) * 16 +
                                           ((ks * 4 + quad) ^ l15)) * 8];
    // gate GEMM0 weights, then immediately issue GEMM1's 16 loads
    VMW4(bW0[0], bW0[1], bW0[2], bW0[3]);
    #pragma unroll
    for (int ni = 0; ni < 4; ++ni) {
      const int n = (npar + ni * 8) * 16 + l15;
      const uint16_t* bp = wb + BOFF_W1T + n * 128 + quad * 8;
      #pragma unroll
      for (int ks = 0; ks < 4; ++ks)
        bW1[ni][ks] = gl16(bp + ks * 32);
    }
    float4v acc[2] = {{0.f, 0.f, 0.f, 0.f}, {0.f, 0.f, 0.f, 0.f}};
    #pragma unroll
    for (int mf = 0; mf < 2; ++mf)
      #pragma unroll
      for (int ks = 0; ks < 4; ++ks)
        acc[mf] = __builtin_amdgcn_mfma_f32_16x16x32_bf16(af[mf][ks], bW0[ks],
                                                          acc[mf], 0, 0, 0);
    #pragma unroll
    for (int mf = 0; mf < 2; ++mf)
      #pragma unroll
      for (int r = 0; r < 4; ++r) {
        const int row = mf * 16 + quad * 4 + r;
        float v = acc[mf][r] + rpre[mf][r];
        smid[mf][r] = v;
        bufS[(row * 16 + ((nG >> 3) ^ (row & 15))) * 8 + (nG & 7)] = f2b(v);
      }
  }
  bar_lds();

  short8 bB2[16];                        // GEMM2 weights (issued in GEMM1)

  // ---- GEMM1: H = relu(smid x W1 + b1)  (N=512, K=128) ----
  {
    short8 af[2][4];
    #pragma unroll
    for (int mf = 0; mf < 2; ++mf)
      #pragma unroll
      for (int ks = 0; ks < 4; ++ks)
        af[mf][ks] = *(const short8*)&bufS[((mf * 16 + l15) * 16 +
                                           ((ks * 4 + quad) ^ l15)) * 8];
    // gate GEMM1 weights, then issue GEMM2's 16 loads
    VMW8(bW1[0][0], bW1[0][1], bW1[0][2], bW1[0][3],
         bW1[1][0], bW1[1][1], bW1[1][2], bW1[1][3]);
    VMW8(bW1[2][0], bW1[2][1], bW1[2][2], bW1[2][3],
         bW1[3][0], bW1[3][1], bW1[3][2], bW1[3][3]);
    {
      const uint16_t* bp = wb + BOFF_W2T + nG * 512 + quad * 8;
      #pragma unroll
      for (int k8 = 0; k8 < 16; ++k8)
        bB2[k8] = gl16(bp + k8 * 32);
    }
    #pragma unroll
    for (int ni = 0; ni < 4; ++ni) {
      const int n = (npar + ni * 8) * 16 + l15;
      float4v acc[2] = {{0.f, 0.f, 0.f, 0.f}, {0.f, 0.f, 0.f, 0.f}};
      #pragma unroll
      for (int mf = 0; mf < 2; ++mf)
        #pragma unroll
        for (int ks = 0; ks < 4; ++ks)
          acc[mf] = __builtin_amdgcn_mfma_f32_16x16x32_bf16(
              af[mf][ks], bW1[ni][ks], acc[mf], 0, 0, 0);
      const float bias = bias1v[ni];
      #pragma unroll
      for (int mf = 0; mf < 2; ++mf)
        #pragma unroll
        for (int r = 0; r < 4; ++r) {
          const int row = mf * 16 + quad * 4 + r;
          bufH[(row * 64 + ((n >> 3) ^ (row & 15))) * 8 + (n & 7)] =
              f2b(fmaxf(acc[mf][r] + bias, 0.f));
        }
    }
  }
  bar_lds();

  short8 bW3[4];                         // GEMM3 weights (issued in GEMM2)

  // ---- GEMM2: R = smid + H x W2 + b2  (N=128, K=512) ----
  {
    // gate GEMM2 weights, then issue GEMM3's 4 loads
    VMW8(bB2[0], bB2[1], bB2[2],  bB2[3],  bB2[4],  bB2[5],  bB2[6],  bB2[7]);
    VMW8(bB2[8], bB2[9], bB2[10], bB2[11], bB2[12], bB2[13], bB2[14], bB2[15]);
    {
      const uint16_t* bp3 = wb + BOFF_WUP + nG * 128 + quad * 8;
      bW3[0] = gl16(bp3);       bW3[1] = gl16(bp3 + 32);
      bW3[2] = gl16(bp3 + 64);  bW3[3] = gl16(bp3 + 96);
    }
    float4v acc0 = {0.f, 0.f, 0.f, 0.f};
    float4v acc1 = {0.f, 0.f, 0.f, 0.f};
    #pragma unroll
    for (int half = 0; half < 2; ++half) {
      #pragma unroll
      for (int qtr = 0; qtr < 2; ++qtr) {
        short8 a0[4], a1[4];
        #pragma unroll
        for (int k4 = 0; k4 < 4; ++k4) {
          const int ks = half * 8 + qtr * 4 + k4;
          a0[k4] = *(const short8*)&bufH[(l15 * 64 +
                                         ((ks * 4 + quad) ^ l15)) * 8];
          a1[k4] = *(const short8*)&bufH[((16 + l15) * 64 +
                                         ((ks * 4 + quad) ^ l15)) * 8];
        }
        #pragma unroll
        for (int k4 = 0; k4 < 4; ++k4) {
          const int ks = half * 8 + qtr * 4 + k4;
          acc0 = __builtin_amdgcn_mfma_f32_16x16x32_bf16(
              a0[k4], bB2[ks], acc0, 0, 0, 0);
          acc1 = __builtin_amdgcn_mfma_f32_16x16x32_bf16(
              a1[k4], bB2[ks], acc1, 0, 0, 0);
        }
      }
    }
    #pragma unroll
    for (int r = 0; r < 4; ++r) {
      const int row0 = quad * 4 + r;
      const int row1 = 16 + quad * 4 + r;
      bufZ[(row0 * 16 + ((nG >> 3) ^ (row0 & 15))) * 8 + (nG & 7)] =
          f2b(acc0[r] + bias2 + smid[0][r]);
      bufZ[(row1 * 16 + ((nG >> 3) ^ (row1 & 15))) * 8 + (nG & 7)] =
          f2b(acc1[r] + bias2 + smid[1][r]);
    }
  }
  bar_lds();

  // ---- GEMM3: logits = R x WUP^T -> DENSE table store (L2-resident) ----
  {
    short8 ar[2][4];
    #pragma unroll
    for (int mf = 0; mf < 2; ++mf)
      #pragma unroll
      for (int ks = 0; ks < 4; ++ks)
        ar[mf][ks] = *(const short8*)&bufZ[((mf * 16 + l15) * 16 +
                                           ((ks * 4 + quad) ^ l15)) * 8];
    VMW4(bW3[0], bW3[1], bW3[2], bW3[3]);
    float4v acc[2] = {{0.f, 0.f, 0.f, 0.f}, {0.f, 0.f, 0.f, 0.f}};
    #pragma unroll
    for (int mf = 0; mf < 2; ++mf)
      #pragma unroll
      for (int ks = 0; ks < 4; ++ks)
        acc[mf] = __builtin_amdgcn_mfma_f32_16x16x32_bf16(ar[mf][ks], bW3[ks],
                                                          acc[mf], 0, 0, 0);
    if (nG < NVOCAB) {
      #pragma unroll
      for (int mf = 0; mf < 2; ++mf)
        #pragma unroll
        for (int r = 0; r < 4; ++r) {
          const int row = mf * 16 + quad * 4 + r;
          const int pair = blk * PAIRS_PB + (row >> 1);
          if (pair < NPAIR)
            table[pair * 226 + (row & 1) * 113 + nG] = acc[mf][r];
        }
    }
  }
  #undef ROW_OF
}

// ---------------- K3: gather — grid-stride (G11: cap blocks, not 58k) -----
__global__ void __launch_bounds__(256) gather_kernel(
    const uint32_t* __restrict__ x_raw, const f2v* __restrict__ table2,
    f2v* __restrict__ out2, int total) {
  // per-wave int64 self-detect, hoisted out of the loop
  uint32_t xs = x_raw[2 * (threadIdx.x & 63) + 1];
  unsigned long long nz = __ballot(xs != 0u);
  const int is64 = (nz == 0ull);

  const int stride = gridDim.x * 256;
  for (int i = blockIdx.x * 256 + threadIdx.x; i < total; i += stride) {
    const int b = i / NVOCAB;
    const int j = i - b * NVOCAB;
    int t0, t1;
    if (is64) {
      t0 = (int)x_raw[4 * b];
      t1 = (int)x_raw[4 * b + 2];
    } else {
      t0 = (int)x_raw[2 * b];
      t1 = (int)x_raw[2 * b + 1];
    }
    t0 = min(max(t0, 0), NVOCAB - 1);
    t1 = min(max(t1, 0), NVOCAB - 1);
    const int pair = t0 * NVOCAB + t1;
    f2v v = table2[(size_t)pair * NVOCAB + j];
    __builtin_nontemporal_store(v, &out2[i]);
  }
}

extern "C" void kernel_launch(void* const* d_in, const int* in_sizes, int n_in,
                              void* d_out, int out_size, void* d_ws, size_t ws_size,
                              hipStream_t stream) {
  // ws layout (byte offsets)
  float*    wf        = (float*)((char*)d_ws + 256);             // biases only
  float*    resid_pre = (float*)((char*)d_ws + 905984);
  float*    qt        = (float*)((char*)d_ws + 1021696);
  float*    kt        = (float*)((char*)d_ws + 1137408);
  float*    vt        = (float*)((char*)d_ws + 1253120);
  float*    table     = (float*)((char*)d_ws + 1368832);         // 11543176 B
  uint16_t* wb        = (uint16_t*)((char*)d_ws + 12912016);     // 327680 B

  const int B = in_sizes[0] / 2;

  SrcPtrs sp;
  for (int i = 0; i < 11; ++i) sp.p[i] = d_in[i + 1];

  // 226 qkv + 427 wb + 2 bias = 655 blocks
  build_kernel<<<655, 384, 0, stream>>>(sp, wf, resid_pre, qt, kt, vt, wb);

  const int nblk = (NPAIR + PAIRS_PB - 1) / PAIRS_PB;  // 799
  pair_mfma_kernel<<<nblk, 512, 0, stream>>>(resid_pre, qt, kt, vt, wf, wb,
                                             table);

  // grid-stride gather: 2048 blocks (G11), not one block per 256 elements
  const int total = B * NVOCAB;   // f2v elements of out
  gather_kernel<<<2048, 256, 0, stream>>>(
      (const uint32_t*)d_in[0], (const f2v*)table, (f2v*)d_out, total);
}